// Round 1
// baseline (341.570 us; speedup 1.0000x reference)
//
#include <hip/hip_runtime.h>
#include <hip/hip_bf16.h>
#include <climits>
#include <cstdint>

#define NROWS   524288
#define KDIM    128
#define CCOLS   256      // combined cols: 0..127 = sketch MLP, 128..255 = max MLP
#define NGRAPH  64
#define NSTROKE 8192
#define EPSF    1e-5f

typedef __bf16 bf16x8 __attribute__((ext_vector_type(8)));
typedef float  f32x4  __attribute__((ext_vector_type(4)));

// ws layout (bytes)
#define WT_OFF    0                         // ushort bf16 Wt[256][128]  (col-major weights)
#define CSUM_OFF  65536                     // float[256]
#define CSQ_OFF   66560                     // float[256]
#define ST_OFF    67584                     // int/float [8192][128] stroke max table
#define GT_OFF    (ST_OFF + NSTROKE*KDIM*4) // int/float [64][128] graph max table
// total = 4,294,656 bytes (~4.1 MB)

__device__ __forceinline__ unsigned short f2bf(float f) {
  unsigned int u = __float_as_uint(f);
  u += 0x7fffu + ((u >> 16) & 1u);   // RNE
  return (unsigned short)(u >> 16);
}
__device__ __forceinline__ float bf2f(unsigned short u) {
  return __uint_as_float(((unsigned int)u) << 16);
}
// order-preserving float->int key (for atomicMax)
__device__ __forceinline__ int fkey(float f) {
  int b = __float_as_int(f);
  return b >= 0 ? b : (b ^ 0x7fffffff);
}
__device__ __forceinline__ float fdec(int k) {
  int b = k >= 0 ? k : (k ^ 0x7fffffff);
  return __int_as_float(b);
}

// ---------------- init: weights -> bf16 col-major; clear sums + max tables ----
__global__ void k_init(const float* __restrict__ Wmax, const float* __restrict__ Wsk,
                       unsigned char* __restrict__ ws) {
  unsigned short* wt = (unsigned short*)(ws + WT_OFF);
  float* csum = (float*)(ws + CSUM_OFF);
  float* csq  = (float*)(ws + CSQ_OFF);
  int* st = (int*)(ws + ST_OFF);
  int* gt = (int*)(ws + GT_OFF);
  int i = blockIdx.x * blockDim.x + threadIdx.x;
  const int total = NSTROKE * KDIM;   // 1048576, grid covers exactly
  for (; i < total; i += gridDim.x * blockDim.x) {
    st[i] = INT_MIN;
    if (i < NGRAPH * KDIM) gt[i] = INT_MIN;
    if (i < CCOLS) { csum[i] = 0.f; csq[i] = 0.f; }
    if (i < CCOLS * KDIM) {
      int c = i / KDIM, k = i % KDIM;
      float w = (c < 128) ? Wsk[k * 128 + c] : Wmax[k * 128 + (c - 128)];
      wt[i] = f2bf(w);   // wt[c][k]
    }
  }
}

// ---------------- pass1: fused GEMM + col sums + raw segment max ----------------
// 256 threads (4 waves). Row tile = 64, wave w owns combined cols [64w,64w+64).
// B (weights) live in registers; x staged to XOR-swizzled bf16 LDS; h dumped to
// XOR-swizzled bf16 LDS for the column-threaded reduction phase.
__global__ __launch_bounds__(256) void k_pass1(const float* __restrict__ x,
                                               const int* __restrict__ batch,
                                               const int* __restrict__ stroke,
                                               unsigned char* __restrict__ ws) {
  __shared__ __align__(16) unsigned short xs[64 * 128];  // 16 KB
  __shared__ __align__(16) unsigned short hs[64 * 256];  // 32 KB
  const unsigned short* wt = (const unsigned short*)(ws + WT_OFF);
  float* csum = (float*)(ws + CSUM_OFF);
  float* csq  = (float*)(ws + CSQ_OFF);
  int* st = (int*)(ws + ST_OFF);
  int* gt = (int*)(ws + GT_OFF);

  const int tid  = threadIdx.x;
  const int lane = tid & 63;
  const int wv   = tid >> 6;   // wave 0..3
  const int lr   = lane & 15;  // frag row/col
  const int lg   = lane >> 4;  // frag k-group

  // B fragments once per block: lane holds Wt[col = c0+n*16+lr][k = ks*32+lg*8 ..+7]
  bf16x8 bfrag[4][4];
#pragma unroll
  for (int ks = 0; ks < 4; ++ks)
#pragma unroll
    for (int n = 0; n < 4; ++n) {
      int col = wv * 64 + n * 16 + lr;
      int k   = ks * 32 + lg * 8;
      bfrag[ks][n] = *(const bf16x8*)(wt + col * KDIM + k);
    }

  float sum_acc = 0.f, sq_acc = 0.f;                 // this thread's column (= tid)
  const int* __restrict__ segp = (tid < 128) ? stroke : batch;  // wave-uniform

  for (int ti = 0; ti < 4; ++ti) {
    const int tile = blockIdx.x * 4 + ti;
    const int row0 = tile * 64;

    // ---- stage x tile (64x128 fp32 -> bf16, swizzled) ----
#pragma unroll
    for (int it = 0; it < 4; ++it) {
      int e  = it * 2048 + tid * 8;
      int r  = e >> 7;
      int kg = (e & 127) >> 3;
      const float* src = x + (size_t)(row0 + r) * KDIM + kg * 8;
      f32x4 v0 = *(const f32x4*)src;
      f32x4 v1 = *(const f32x4*)(src + 4);
      union { bf16x8 v; unsigned short u[8]; } pk;
      pk.u[0] = f2bf(v0[0]); pk.u[1] = f2bf(v0[1]); pk.u[2] = f2bf(v0[2]); pk.u[3] = f2bf(v0[3]);
      pk.u[4] = f2bf(v1[0]); pk.u[5] = f2bf(v1[1]); pk.u[6] = f2bf(v1[2]); pk.u[7] = f2bf(v1[3]);
      *(bf16x8*)(xs + r * KDIM + ((kg ^ (r & 7)) << 3)) = pk.v;
    }
    __syncthreads();

    // ---- MFMA: 64 rows x 64 cols per wave ----
    f32x4 acc[4][4];
#pragma unroll
    for (int m = 0; m < 4; ++m)
#pragma unroll
      for (int n = 0; n < 4; ++n) { f32x4 z = {0.f, 0.f, 0.f, 0.f}; acc[m][n] = z; }

#pragma unroll
    for (int ks = 0; ks < 4; ++ks) {
      bf16x8 af[4];
#pragma unroll
      for (int m = 0; m < 4; ++m) {
        int r  = m * 16 + lr;
        int kg = ks * 4 + lg;
        af[m] = *(const bf16x8*)(xs + r * KDIM + ((kg ^ (r & 7)) << 3));
      }
#pragma unroll
      for (int m = 0; m < 4; ++m)
#pragma unroll
        for (int n = 0; n < 4; ++n)
          acc[m][n] = __builtin_amdgcn_mfma_f32_16x16x32_bf16(af[m], bfrag[ks][n], acc[m][n], 0, 0, 0);
    }

    // ---- dump h to LDS (bf16, swizzled). D layout: col=lane&15, row=(lane>>4)*4+reg ----
#pragma unroll
    for (int m = 0; m < 4; ++m)
#pragma unroll
      for (int n = 0; n < 4; ++n)
#pragma unroll
        for (int rg = 0; rg < 4; ++rg) {
          int r = m * 16 + lg * 4 + rg;
          int c = wv * 64 + n * 16 + lr;
          int byte = r * 512 + ((c * 2) ^ (((r >> 2) & 7) << 4));
          *(unsigned short*)((char*)hs + byte) = f2bf(acc[m][n][rg]);
        }
    __syncthreads();

    // ---- reduction: thread tid owns combined column tid over the 64 tile rows ----
    int curseg = -1; float runmax = -3.4e38f;
    for (int r = 0; r < 64; ++r) {
      int byte = r * 512 + ((tid * 2) ^ (((r >> 2) & 7) << 4));
      float v = bf2f(*(const unsigned short*)((const char*)hs + byte));
      sum_acc += v; sq_acc += v * v;
      int seg = segp[row0 + r];
      if (seg != curseg) {
        if (curseg >= 0) {
          int key = fkey(runmax);
          if (tid < 128) atomicMax(&st[curseg * KDIM + tid], key);
          else           atomicMax(&gt[curseg * KDIM + (tid - 128)], key);
        }
        curseg = seg; runmax = v;
      } else {
        runmax = fmaxf(runmax, v);
      }
    }
    {
      int key = fkey(runmax);
      if (tid < 128) atomicMax(&st[curseg * KDIM + tid], key);
      else           atomicMax(&gt[curseg * KDIM + (tid - 128)], key);
    }
    __syncthreads();
  }

  atomicAdd(&csum[tid], sum_acc);
  atomicAdd(&csq[tid], sq_acc);
}

// ---------------- pass2: normalize + ReLU max tables in place -------------------
// relu/affine commute with max (scale > 0); bias b cancels against the mean.
__global__ void k_norm(const float* __restrict__ g_max, const float* __restrict__ be_max,
                       const float* __restrict__ g_sk,  const float* __restrict__ be_sk,
                       unsigned char* __restrict__ ws) {
  float* csum = (float*)(ws + CSUM_OFF);
  float* csq  = (float*)(ws + CSQ_OFF);
  int* st = (int*)(ws + ST_OFF);
  int* gt = (int*)(ws + GT_OFF);
  int i = blockIdx.x * blockDim.x + threadIdx.x;
  const int totalS = NSTROKE * KDIM;
  const int total  = totalS + NGRAPH * KDIM;
  if (i >= total) return;
  int* tp; int c, cc; float gg, bb;
  if (i < totalS) { tp = st + i; c = i & 127; cc = c;       gg = g_sk[c];  bb = be_sk[c]; }
  else { int j = i - totalS; tp = gt + j; c = j & 127; cc = 128 + c; gg = g_max[c]; bb = be_max[c]; }
  const float invN = 1.0f / (float)NROWS;
  float mu    = csum[cc] * invN;
  float var   = csq[cc] * invN - mu * mu;
  float scale = gg * rsqrtf(var + EPSF);
  float v = fdec(*tp);
  float o = fmaxf(0.f, (v - mu) * scale + bb);
  *(float*)tp = o;
}

// ---------------- pass3: broadcast-gather to output -----------------------------
// One wave per 64 consecutive rows; lane writes one float4 of the 256-col row.
__global__ __launch_bounds__(256) void k_out(const int* __restrict__ batch,
                                             const int* __restrict__ stroke,
                                             const unsigned char* __restrict__ ws,
                                             float* __restrict__ out) {
  const f32x4* stT = (const f32x4*)(ws + ST_OFF);
  const f32x4* gtT = (const f32x4*)(ws + GT_OFF);
  const int wvid = blockIdx.x * 4 + (threadIdx.x >> 6);
  const int lane = threadIdx.x & 63;
  const int row0 = wvid * 64;
  f32x4* out4 = (f32x4*)out;
  for (int r = 0; r < 64; ++r) {
    int row = row0 + r;
    const f32x4* src;
    if (lane < 32) src = stT + (size_t)stroke[row] * 32 + lane;
    else           src = gtT + (size_t)batch[row]  * 32 + (lane - 32);
    out4[(size_t)row * 64 + lane] = *src;
  }
}

extern "C" void kernel_launch(void* const* d_in, const int* in_sizes, int n_in,
                              void* d_out, int out_size, void* d_ws, size_t ws_size,
                              hipStream_t stream) {
  const float* x      = (const float*)d_in[0];
  const int*   batch  = (const int*)d_in[1];
  const int*   stroke = (const int*)d_in[2];
  const float* Wmax   = (const float*)d_in[3];
  // d_in[4] = b_max: cancels in BN, unused
  const float* g_max  = (const float*)d_in[5];
  const float* be_max = (const float*)d_in[6];
  const float* Wsk    = (const float*)d_in[7];
  // d_in[8] = b_sk: unused
  const float* g_sk   = (const float*)d_in[9];
  const float* be_sk  = (const float*)d_in[10];
  unsigned char* ws = (unsigned char*)d_ws;
  float* out = (float*)d_out;

  k_init <<<2048, 512, 0, stream>>>(Wmax, Wsk, ws);
  k_pass1<<<2048, 256, 0, stream>>>(x, batch, stroke, ws);
  k_norm <<<4128, 256, 0, stream>>>(g_max, be_max, g_sk, be_sk, ws);
  k_out  <<<2048, 256, 0, stream>>>(batch, stroke, ws, out);
}

// Round 2
// 250.098 us; speedup vs baseline: 1.3657x; 1.3657x over previous
//
#include <hip/hip_runtime.h>
#include <hip/hip_bf16.h>
#include <climits>
#include <cstdint>
#include <cfloat>

#define NROWS   524288
#define KDIM    128
#define NGRAPH  64
#define NSTROKE 8192
#define EPSF    1e-5f

typedef __bf16 bf16x8 __attribute__((ext_vector_type(8)));
typedef float  f32x4  __attribute__((ext_vector_type(4)));
typedef unsigned short u16x4 __attribute__((ext_vector_type(4)));

// ws layout (bytes)
#define WT_OFF    0                         // ushort bf16 Wt[256][128] (col-major)
#define CSUM_OFF  65536                     // float[256]
#define CSQ_OFF   66560                     // float[256]
#define ST_OFF    67584                     // int [8192][128] stroke max (int-key)
#define GT_OFF    (ST_OFF + NSTROKE*KDIM*4) // int [64][128] graph max (int-key)

__device__ __forceinline__ unsigned short f2bf(float f) {
  unsigned int u = __float_as_uint(f);
  u += 0x7fffu + ((u >> 16) & 1u);   // RNE
  return (unsigned short)(u >> 16);
}
__device__ __forceinline__ float bf2f(unsigned short u) {
  return __uint_as_float(((unsigned int)u) << 16);
}
// order-preserving float<->int key (for atomicMax)
__device__ __forceinline__ int fkey(float f) {
  int b = __float_as_int(f);
  return b >= 0 ? b : (b ^ 0x7fffffff);
}
__device__ __forceinline__ float fdec(int k) {
  int b = k >= 0 ? k : (k ^ 0x7fffffff);
  return __int_as_float(b);
}

// ---------------- init: weights -> bf16 col-major; clear sums + max tables ----
__global__ void k_init(const float* __restrict__ Wmax, const float* __restrict__ Wsk,
                       unsigned char* __restrict__ ws) {
  unsigned short* wt = (unsigned short*)(ws + WT_OFF);
  float* csum = (float*)(ws + CSUM_OFF);
  float* csq  = (float*)(ws + CSQ_OFF);
  int* st = (int*)(ws + ST_OFF);
  int* gt = (int*)(ws + GT_OFF);
  int i = blockIdx.x * blockDim.x + threadIdx.x;
  const int total = NSTROKE * KDIM;   // 1048576
  for (; i < total; i += gridDim.x * blockDim.x) {
    st[i] = INT_MIN;
    if (i < NGRAPH * KDIM) gt[i] = INT_MIN;
    if (i < 256) { csum[i] = 0.f; csq[i] = 0.f; }
    if (i < 256 * KDIM) {
      int c = i / KDIM, k = i % KDIM;
      float w = (c < 128) ? Wsk[k * 128 + c] : Wmax[k * 128 + (c - 128)];
      wt[i] = f2bf(w);   // wt[c][k]
    }
  }
}

// ---------------- pass1: fused GEMM + col sums (in-reg) + raw segment max ------
// 256 threads (4 waves), 8 row-tiles of 64 per block. Wave w owns cols [64w,64w+64).
// h dumped col-major bf16 [c][64] with 16B-chunk XOR swizzle for vector reduce.
__global__ __launch_bounds__(256) void k_pass1(const float* __restrict__ x,
                                               const int* __restrict__ batch,
                                               const int* __restrict__ stroke,
                                               unsigned char* __restrict__ ws) {
  __shared__ __align__(16) unsigned short xs[64 * 128];  // 16 KB (row-major, swz)
  __shared__ __align__(16) unsigned short hs[256 * 64];  // 32 KB (col-major, swz)
  __shared__ int ss[64];   // stroke id per tile row
  __shared__ int gg[64];   // graph id per tile row
  const unsigned short* wt = (const unsigned short*)(ws + WT_OFF);
  float* csum = (float*)(ws + CSUM_OFF);
  float* csq  = (float*)(ws + CSQ_OFF);
  int* st = (int*)(ws + ST_OFF);
  int* gt = (int*)(ws + GT_OFF);

  const int tid  = threadIdx.x;
  const int lane = tid & 63;
  const int wv   = tid >> 6;   // wave 0..3
  const int lr   = lane & 15;
  const int lg   = lane >> 4;

  // B fragments: lane holds Wt[col = wv*64+n*16+lr][k = ks*32+lg*8 ..+7]
  bf16x8 bfrag[4][4];
#pragma unroll
  for (int ks = 0; ks < 4; ++ks)
#pragma unroll
    for (int n = 0; n < 4; ++n) {
      int c = wv * 64 + n * 16 + lr;
      int k = ks * 32 + lg * 8;
      bfrag[ks][n] = *(const bf16x8*)(wt + c * KDIM + k);
    }

  float sumn[4] = {0.f, 0.f, 0.f, 0.f};
  float sqn[4]  = {0.f, 0.f, 0.f, 0.f};
  int* mp = (tid < 128) ? (st + tid) : (gt + (tid - 128));

  for (int ti = 0; ti < 8; ++ti) {
    const int row0 = (blockIdx.x * 8 + ti) * 64;

    // ---- stage x tile (64x128 fp32 -> bf16, swizzled row-major) ----
#pragma unroll
    for (int it = 0; it < 4; ++it) {
      int e  = it * 2048 + tid * 8;
      int r  = e >> 7;
      int kg = (e & 127) >> 3;
      const float* src = x + (size_t)(row0 + r) * KDIM + kg * 8;
      f32x4 v0 = *(const f32x4*)src;
      f32x4 v1 = *(const f32x4*)(src + 4);
      union { bf16x8 v; unsigned short u[8]; } pk;
      pk.u[0] = f2bf(v0[0]); pk.u[1] = f2bf(v0[1]); pk.u[2] = f2bf(v0[2]); pk.u[3] = f2bf(v0[3]);
      pk.u[4] = f2bf(v1[0]); pk.u[5] = f2bf(v1[1]); pk.u[6] = f2bf(v1[2]); pk.u[7] = f2bf(v1[3]);
      *(bf16x8*)(xs + r * KDIM + ((kg ^ (r & 7)) << 3)) = pk.v;
    }
    if (tid < 64)       ss[tid]      = stroke[row0 + tid];
    else if (tid < 128) gg[tid - 64] = batch[row0 + tid - 64];
    __syncthreads();

    // ---- MFMA: 64 rows x 64 cols per wave ----
    f32x4 acc[4][4];
#pragma unroll
    for (int m = 0; m < 4; ++m)
#pragma unroll
      for (int n = 0; n < 4; ++n) { f32x4 z = {0.f, 0.f, 0.f, 0.f}; acc[m][n] = z; }

#pragma unroll
    for (int ks = 0; ks < 4; ++ks) {
      bf16x8 af[4];
#pragma unroll
      for (int m = 0; m < 4; ++m) {
        int r  = m * 16 + lr;
        int kg = ks * 4 + lg;
        af[m] = *(const bf16x8*)(xs + r * KDIM + ((kg ^ (r & 7)) << 3));
      }
#pragma unroll
      for (int m = 0; m < 4; ++m)
#pragma unroll
        for (int n = 0; n < 4; ++n)
          acc[m][n] = __builtin_amdgcn_mfma_f32_16x16x32_bf16(af[m], bfrag[ks][n], acc[m][n], 0, 0, 0);
    }

    // ---- column sums/sumsq straight from accumulators (f32, no LDS trip) ----
#pragma unroll
    for (int n = 0; n < 4; ++n) {
      float s = 0.f, q = 0.f;
#pragma unroll
      for (int m = 0; m < 4; ++m)
#pragma unroll
        for (int rg = 0; rg < 4; ++rg) { float v = acc[m][n][rg]; s += v; q = fmaf(v, v, q); }
      sumn[n] += s; sqn[n] += q;
    }

    // ---- dump h col-major bf16 [c][64], 16B-chunk XOR swizzle, vector b64 ----
    // addr(c,row) = c*128 + ((row>>3 ^ (c&7))<<4) + (row&7)*2
#pragma unroll
    for (int m = 0; m < 4; ++m)
#pragma unroll
      for (int n = 0; n < 4; ++n) {
        u16x4 p;
#pragma unroll
        for (int rg = 0; rg < 4; ++rg) p[rg] = f2bf(acc[m][n][rg]);
        int c    = wv * 64 + n * 16 + lr;
        int rowb = m * 16 + lg * 4;
        int byte = (c << 7) + (((rowb >> 3) ^ (c & 7)) << 4) + ((rowb & 7) << 1);
        *(u16x4*)((char*)hs + byte) = p;
      }
    __syncthreads();

    // ---- segment max: thread owns combined column tid; 8 x ds_read_b128 ----
    const int* segl = (tid < 128) ? ss : gg;
    int curseg = segl[0]; float runmax = -FLT_MAX;
#pragma unroll
    for (int J = 0; J < 8; ++J) {
      int byte = (tid << 7) + ((J ^ (tid & 7)) << 4);
      union { bf16x8 v; unsigned short u[8]; } hv;
      hv.v = *(const bf16x8*)((const char*)hs + byte);
#pragma unroll
      for (int rr = 0; rr < 8; ++rr) {
        float v = bf2f(hv.u[rr]);
        int seg = segl[J * 8 + rr];
        if (seg != curseg) {
          atomicMax(&mp[curseg * KDIM], fkey(runmax));
          curseg = seg; runmax = v;
        } else {
          runmax = fmaxf(runmax, v);
        }
      }
    }
    atomicMax(&mp[curseg * KDIM], fkey(runmax));
    __syncthreads();
  }

  // ---- finalize sums: reduce over the 4 k-group lanes, 1 atomic per column ----
#pragma unroll
  for (int n = 0; n < 4; ++n) {
    sumn[n] += __shfl_xor(sumn[n], 16);
    sumn[n] += __shfl_xor(sumn[n], 32);
    sqn[n]  += __shfl_xor(sqn[n], 16);
    sqn[n]  += __shfl_xor(sqn[n], 32);
  }
  float s = 0.f, q = 0.f;
#pragma unroll
  for (int n = 0; n < 4; ++n) if (n == lg) { s = sumn[n]; q = sqn[n]; }  // static select
  atomicAdd(&csum[tid], s);   // col = wv*64 + lg*16 + lr == tid
  atomicAdd(&csq[tid], q);
}

// ---------------- out: gather + BN(affine)+ReLU on the fly + stream write ------
// One wave per 64 rows; lane<32 -> sketch cols 4l..4l+3, lane>=32 -> max cols.
__global__ __launch_bounds__(256) void k_out(const int* __restrict__ batch,
                                             const int* __restrict__ stroke,
                                             const float* __restrict__ g_max,
                                             const float* __restrict__ be_max,
                                             const float* __restrict__ g_sk,
                                             const float* __restrict__ be_sk,
                                             const unsigned char* __restrict__ ws,
                                             float* __restrict__ out) {
  const float* csum = (const float*)(ws + CSUM_OFF);
  const float* csq  = (const float*)(ws + CSQ_OFF);
  const int* st = (const int*)(ws + ST_OFF);
  const int* gt = (const int*)(ws + GT_OFF);

  const int lane = threadIdx.x & 63;
  const int wvid = blockIdx.x * 4 + (threadIdx.x >> 6);
  const int row0 = wvid * 64;
  const bool isS = lane < 32;
  const int  cg  = (isS ? lane : lane - 32) * 4;      // column group in its table
  const int* tab  = isS ? st : gt;
  const int* idxp = isS ? stroke : batch;
  const float* gv = isS ? g_sk : g_max;
  const float* bv = isS ? be_sk : be_max;

  const float invN = 1.0f / (float)NROWS;
  f32x4 mu, sc, bb;
#pragma unroll
  for (int j = 0; j < 4; ++j) {
    int cc = (isS ? 0 : 128) + cg + j;
    float m  = csum[cc] * invN;
    float vr = csq[cc] * invN - m * m;
    mu[j] = m;
    sc[j] = gv[cg + j] * rsqrtf(vr + EPSF);
    bb[j] = bv[cg + j];
  }

  f32x4* out4 = (f32x4*)out;
#pragma unroll 4
  for (int r = 0; r < 64; ++r) {
    int row = row0 + r;
    int seg = idxp[row];
    const int4 k4 = *(const int4*)(tab + (size_t)seg * KDIM + cg);
    f32x4 v;
    v[0] = fdec(k4.x); v[1] = fdec(k4.y); v[2] = fdec(k4.z); v[3] = fdec(k4.w);
#pragma unroll
    for (int j = 0; j < 4; ++j) v[j] = fmaxf(0.f, (v[j] - mu[j]) * sc[j] + bb[j]);
    __builtin_nontemporal_store(v, &out4[(size_t)row * 64 + lane]);
  }
}

extern "C" void kernel_launch(void* const* d_in, const int* in_sizes, int n_in,
                              void* d_out, int out_size, void* d_ws, size_t ws_size,
                              hipStream_t stream) {
  const float* x      = (const float*)d_in[0];
  const int*   batch  = (const int*)d_in[1];
  const int*   stroke = (const int*)d_in[2];
  const float* Wmax   = (const float*)d_in[3];
  const float* g_max  = (const float*)d_in[5];
  const float* be_max = (const float*)d_in[6];
  const float* Wsk    = (const float*)d_in[7];
  const float* g_sk   = (const float*)d_in[9];
  const float* be_sk  = (const float*)d_in[10];
  unsigned char* ws = (unsigned char*)d_ws;
  float* out = (float*)d_out;

  k_init <<<2048, 512, 0, stream>>>(Wmax, Wsk, ws);
  k_pass1<<<1024, 256, 0, stream>>>(x, batch, stroke, ws);
  k_out  <<<2048, 256, 0, stream>>>(batch, stroke, g_max, be_max, g_sk, be_sk, ws, out);
}